// Round 8
// baseline (423.307 us; speedup 1.0000x reference)
//
#include <hip/hip_runtime.h>
#include <hip/hip_fp16.h>
#include <math.h>

#define NN   100000
#define EE   1600000
#define FIN  256
#define NCLS 16
#define NEG  0.2f

#define NEDGE (EE + NN)     // with self-loops
#define WBKT  256           // dsts per bucket
#define NBKT  ((NN + WBKT - 1) / WBKT)   // 391
#define CAP   5120          // per-bucket capacity (mean 4352)
#define ABLK  4096          // edges per binA block
#define NABLK ((NEDGE + ABLK - 1) / ABLK)  // 416

#define NPART 4
#define PSIZE 25000         // src nodes/partition: 3.2MB h1b + 0.8MB al1s slice

// ---- workspace layout (4-byte element offsets) ----
#define OFF_GCNT  0                          // [392] zeroed each call
#define OFF_BASE  392                        // [392]
#define OFF_ROW   784                        // [NN+1]
#define OFF_BKT   100788                     // [NBKT*CAP] packed (src<<8)|dlow
#define OFF_ADJ   (OFF_BKT + NBKT*CAP)       // [NEDGE]
#define OFF_H1B   (OFF_ADJ + NEDGE)          // [NN*64] bf16 (pre-attn values)
#define OFF_H1E   (OFF_H1B + NN*32)          // [NN*64] bf16 (post-ELU)
#define OFF_AL1S  (OFF_H1E + NN*32)          // [NN*8]
#define OFF_AL1D  (OFF_AL1S + NN*8)          // [NN*8]
#define OFF_H2B   (OFF_AL1D + NN*8)          // [NN*16] bf16
#define OFF_AL2S  (OFF_H2B + NN*8)           // [NN]
#define OFF_AL2D  (OFF_AL2S + NN)            // [NN]
// partitioned-agg extension (guarded by ws_size check at launch)
#define OFF_ROW2  (OFF_AL2D + NN)            // [NN*5]  per-(dst,partition) bounds
#define OFF_PVH   (OFF_ROW2 + NN*5 + 8)      // [NPART*NN*32] u32 (2xfp16) NORMALIZED partials
#define OFF_END   (OFF_PVH + NN*128)
// per-(p,dst,head) fp16 weight masses ALIASED onto bkt (dead after k_binC):
// needs NPART*NN*4 = 1.6M u32; bkt region holds NBKT*CAP = 2.0M u32.
#define OFF_PWH   OFF_BKT

__device__ __forceinline__ float lrelu(float x) { return x >= 0.f ? x : NEG * x; }
__device__ __forceinline__ unsigned short f2bf(float x) {
    unsigned u = __float_as_uint(x);
    return (unsigned short)((u + 0x7FFF + ((u >> 16) & 1)) >> 16);   // RNE
}
__device__ __forceinline__ float bf2f(unsigned short b) {
    return __uint_as_float(((unsigned)b) << 16);
}
__device__ __forceinline__ float bflo(unsigned u) { return __uint_as_float(u << 16); }
__device__ __forceinline__ float bfhi(unsigned u) { return __uint_as_float(u & 0xFFFF0000u); }
__device__ __forceinline__ unsigned pack2h(float a, float b) {
    __half2 hh = __floats2half2_rn(a, b);
    return *reinterpret_cast<unsigned*>(&hh);
}
__device__ __forceinline__ float2 unpack2h(unsigned u) {
    __half2 hh = *reinterpret_cast<__half2*>(&u);
    return __half22float2(hh);
}

// ---------- CSR build, phase A: bin edges by dst>>8 ----------
__global__ __launch_bounds__(256) void k_binA(
    const int* __restrict__ esrc, const int* __restrict__ edst,
    int* __restrict__ gcnt, unsigned* __restrict__ bkt)
{
    __shared__ int lcnt[NBKT];
    __shared__ int lbase[NBKT];
    const int t = threadIdx.x;
    const int e0 = blockIdx.x * ABLK;
    for (int i = t; i < NBKT; i += 256) lcnt[i] = 0;
    __syncthreads();

    unsigned wrd[16];
    unsigned short bb[16], ll[16];
    #pragma unroll
    for (int j = 0; j < 16; ++j) {
        int ei = e0 + j * 256 + t;
        bb[j] = 0xFFFFu;
        if (ei < NEDGE) {
            int s, d;
            if (ei < EE) { s = esrc[ei]; d = edst[ei]; } else { s = d = ei - EE; }
            int b = d >> 8;
            wrd[j] = ((unsigned)s << 8) | (unsigned)(d & 255);
            bb[j] = (unsigned short)b;
            ll[j] = (unsigned short)atomicAdd(&lcnt[b], 1);
        }
    }
    __syncthreads();
    for (int i = t; i < NBKT; i += 256)
        lbase[i] = lcnt[i] ? atomicAdd(&gcnt[i], lcnt[i]) : 0;
    __syncthreads();
    #pragma unroll
    for (int j = 0; j < 16; ++j) {
        if (bb[j] != 0xFFFFu) {
            int b = bb[j];
            bkt[(size_t)b * CAP + lbase[b] + ll[j]] = wrd[j];
        }
    }
}

// ---------- CSR build, phase B: scan bucket counts -> bases ----------
__global__ __launch_bounds__(512) void k_scanB(
    const int* __restrict__ gcnt, int* __restrict__ base, int* __restrict__ row)
{
    __shared__ int s[512];
    int t = threadIdx.x;
    int v = (t < NBKT) ? gcnt[t] : 0;
    s[t] = v;
    __syncthreads();
    for (int off = 1; off < 512; off <<= 1) {
        int u = (t >= off) ? s[t - off] : 0;
        __syncthreads();
        s[t] += u;
        __syncthreads();
    }
    if (t <= NBKT) base[t] = s[t] - v;   // exclusive; base[NBKT] = NEDGE
    if (t == 0) row[NN] = NEDGE;
}

// ---------- CSR build, phase C: per-bucket sort -> row + adj (+row2) ----------
__global__ __launch_bounds__(256) void k_binC(
    const int* __restrict__ gcnt, const int* __restrict__ base,
    const unsigned* __restrict__ bkt, int* __restrict__ row, int* __restrict__ adj,
    int* __restrict__ row2, int wr2)
{
    __shared__ unsigned wd[CAP];          // 20 KB raw stage
    __shared__ unsigned srt[CAP];         // 20 KB dst-grouped srcs
    __shared__ int hist[256], pref[256], cnt2[256];
    __shared__ int h4[256][5];            // per-dst partition counters
    const int g = blockIdx.x, t = threadIdx.x;
    const int cn = gcnt[g], bs = base[g];
    hist[t] = 0; cnt2[t] = 0;
    h4[t][0] = 0; h4[t][1] = 0; h4[t][2] = 0; h4[t][3] = 0;
    __syncthreads();
    for (int i = t; i < cn; i += 256) {
        unsigned w = bkt[(size_t)g * CAP + i];
        wd[i] = w;
        atomicAdd(&hist[w & 255], 1);
    }
    __syncthreads();
    int v = hist[t];
    pref[t] = v;
    __syncthreads();
    for (int off = 1; off < 256; off <<= 1) {
        int u = (t >= off) ? pref[t - off] : 0;
        __syncthreads();
        pref[t] += u;
        __syncthreads();
    }
    int ex = pref[t] - v;                 // exclusive local prefix
    int n = g * 256 + t;
    if (n < NN) row[n] = bs + ex;
    pref[t] = ex;
    __syncthreads();
    // scatter into LDS grouped by dlow
    for (int i = t; i < cn; i += 256) {
        unsigned w = wd[i];
        int dl = w & 255;
        int p = atomicAdd(&cnt2[dl], 1);
        srt[pref[dl] + p] = w >> 8;       // src id
    }
    __syncthreads();
    // thread t owns dst n's segment srt[ex .. ex+v)
    for (int k = 0; k < v; ++k) {
        unsigned s = srt[ex + k];
        ++h4[t][s / (unsigned)PSIZE];
    }
    int run = 0;
    #pragma unroll
    for (int b = 0; b < NPART; ++b) {
        int c = h4[t][b];
        if (wr2 && n < NN) row2[n * 5 + b] = bs + ex + run;
        h4[t][b] = ex + run;              // local running start for scatter
        run += c;
    }
    if (wr2 && n < NN) row2[n * 5 + 4] = bs + ex + v;
    for (int k = 0; k < v; ++k) {
        unsigned s = srt[ex + k];
        adj[bs + h4[t][s / (unsigned)PSIZE]++] = (int)s;
    }
}

// ---------- layer 1 GEMM: 64x64 tile, 4x4 register tile; bf16 value output ----------
__global__ __launch_bounds__(256) void k_gemm1(
    const float* __restrict__ x, const float* __restrict__ W1,
    const float* __restrict__ a1s, const float* __restrict__ a1d,
    unsigned short* __restrict__ h1b, float* __restrict__ al1s, float* __restrict__ al1d)
{
    __shared__ float sxT[32][68];
    __shared__ float sW[32][64];
    const int t = threadIdx.x;
    const int n0 = blockIdx.x * 64;
    const int tr = t >> 4, tc = t & 15;

    float acc[4][4] = {};

    for (int kc = 0; kc < 256; kc += 32) {
        __syncthreads();
        #pragma unroll
        for (int it = 0; it < 2; ++it) {
            int i = t + it * 256;
            int r = i >> 3, fj = i & 7;
            int n = n0 + r;
            float4 v = (n < NN) ? *(const float4*)(x + (size_t)n * FIN + kc + fj * 4)
                                : make_float4(0.f, 0.f, 0.f, 0.f);
            sxT[fj * 4 + 0][r] = v.x;
            sxT[fj * 4 + 1][r] = v.y;
            sxT[fj * 4 + 2][r] = v.z;
            sxT[fj * 4 + 3][r] = v.w;
        }
        #pragma unroll
        for (int it = 0; it < 2; ++it) {
            int i = t + it * 256;
            int r = i >> 4, fj = i & 15;
            *(float4*)&sW[r][fj * 4] = *(const float4*)(W1 + (size_t)(kc + r) * 64 + fj * 4);
        }
        __syncthreads();
        #pragma unroll
        for (int k = 0; k < 32; ++k) {
            float4 a = *(const float4*)&sxT[k][tr * 4];
            float4 b = *(const float4*)&sW[k][tc * 4];
            acc[0][0] += a.x * b.x; acc[0][1] += a.x * b.y; acc[0][2] += a.x * b.z; acc[0][3] += a.x * b.w;
            acc[1][0] += a.y * b.x; acc[1][1] += a.y * b.y; acc[1][2] += a.y * b.z; acc[1][3] += a.y * b.w;
            acc[2][0] += a.z * b.x; acc[2][1] += a.z * b.y; acc[2][2] += a.z * b.z; acc[2][3] += a.z * b.w;
            acc[3][0] += a.w * b.x; acc[3][1] += a.w * b.y; acc[3][2] += a.w * b.z; acc[3][3] += a.w * b.w;
        }
    }

    #pragma unroll
    for (int j = 0; j < 4; ++j) {
        int n = n0 + tr * 4 + j;
        if (n < NN) {
            ushort4 v = make_ushort4(f2bf(acc[j][0]), f2bf(acc[j][1]), f2bf(acc[j][2]), f2bf(acc[j][3]));
            *(ushort4*)(h1b + (size_t)n * 64 + tc * 4) = v;
        }
    }

    float sa[4], da[4];
    #pragma unroll
    for (int u = 0; u < 4; ++u) { sa[u] = a1s[tc * 4 + u]; da[u] = a1d[tc * 4 + u]; }
    #pragma unroll
    for (int j = 0; j < 4; ++j) {
        float vs = acc[j][0] * sa[0] + acc[j][1] * sa[1] + acc[j][2] * sa[2] + acc[j][3] * sa[3];
        float vd = acc[j][0] * da[0] + acc[j][1] * da[1] + acc[j][2] * da[2] + acc[j][3] * da[3];
        vs += __shfl_xor(vs, 1, 64);
        vd += __shfl_xor(vd, 1, 64);
        int n = n0 + tr * 4 + j;
        if (!(tc & 1) && n < NN) {
            al1s[n * 8 + (tc >> 1)] = vs;
            al1d[n * 8 + (tc >> 1)] = vd;
        }
    }
}

// ---------- layer 1 aggregation, partition-pinned, exclusive fp16 partials ----------
// p = blockIdx&3: with round-robin blockIdx->XCD dispatch, partition p runs on
// XCDs {p,p+4}; its 3.2MB h1b + 0.8MB al1s slice stays L2-resident.
// Each (p,dst) slot written by exactly ONE 16-lane group (no atomics, no
// cross-XCD coherence dependence). Partials NORMALIZED by the lane's OWN
// per-head mass (y = ax/D_p^(h)); masses stored PER HEAD (R5/R7 bug: only
// head 0's mass was kept -> deterministic 0.109 error, precision-independent).
__global__ __launch_bounds__(256) void k_agg1p(
    const int* __restrict__ row2, const int* __restrict__ adj,
    const float* __restrict__ al1s, const float* __restrict__ al1d,
    const unsigned* __restrict__ h1b2,
    unsigned* __restrict__ pvh, unsigned* __restrict__ pwh)
{
    const int p  = blockIdx.x & 3;
    const int dq = blockIdx.x >> 2;           // 0..NN/16-1
    const int wv = threadIdx.x >> 6, lane = threadIdx.x & 63;
    const int gslot = lane >> 4;              // dst slot within wave
    const int r  = lane & 15;                 // channel quad -> channels 4r..4r+3
    const int h  = r >> 1;                    // head
    const int n  = dq * 16 + wv * 4 + gslot;
    const int e0 = row2[n * 5 + p];
    const int e1 = row2[n * 5 + p + 1];
    const float ald = al1d[n * 8 + h];

    float dsum = 0.f, ax = 0.f, ay = 0.f, bx = 0.f, by = 0.f;
    for (int k = e0; k < e1; k += 2) {
        bool k1ok = (k + 1 < e1);
        int s0 = __builtin_nontemporal_load(adj + k);
        int s1 = __builtin_nontemporal_load(adj + (k1ok ? k + 1 : k));
        float a0 = al1s[s0 * 8 + h];
        float a1 = al1s[s1 * 8 + h];
        uint2 u0 = *(const uint2*)(h1b2 + s0 * 32 + r * 2);
        uint2 u1 = *(const uint2*)(h1b2 + s1 * 32 + r * 2);
        float w0 = __expf(lrelu(a0 + ald));
        float w1 = k1ok ? __expf(lrelu(a1 + ald)) : 0.f;
        dsum += w0 + w1;
        ax += w0 * bflo(u0.x) + w1 * bflo(u1.x);
        ay += w0 * bfhi(u0.x) + w1 * bfhi(u1.x);
        bx += w0 * bflo(u0.y) + w1 * bflo(u1.y);
        by += w0 * bfhi(u0.y) + w1 * bfhi(u1.y);
    }
    float invp = dsum > 0.f ? 1.f / dsum : 0.f;   // empty partition -> zeros
    unsigned o0 = pack2h(ax * invp, ay * invp);
    unsigned o1 = pack2h(bx * invp, by * invp);
    size_t pb = (size_t)(p * NN + n) * 32 + r * 2;
    __builtin_nontemporal_store(o0, pvh + pb);
    __builtin_nontemporal_store(o1, pvh + pb + 1);
    // per-head mass: lane r=2h holds D^(h); pair with D^(h+1) from lane r+2
    float dnx = __shfl_xor(dsum, 2, 64);
    if ((r & 3) == 0)   // r = 0,4,8,12 -> head-pair word (h, h+1), h = r>>1
        __builtin_nontemporal_store(pack2h(dsum, dnx),
                                    pwh + (size_t)(p * NN + n) * 4 + (r >> 2));
}

// ---------- combine: per-head convex recombination + bias + ELU -> h1e ----------
__global__ __launch_bounds__(256) void k_comb1(
    const unsigned* __restrict__ pvh, const unsigned* __restrict__ pwh,
    const float* __restrict__ b1, unsigned* __restrict__ h1e2)
{
    const int t = threadIdx.x;
    const int n = blockIdx.x * 16 + (t >> 4);
    const int r = t & 15;
    const int hsel = (r >> 1) & 1;        // which half of the head-pair word
    float a0 = 0.f, a1 = 0.f, a2 = 0.f, a3 = 0.f, ds = 0.f;
    #pragma unroll
    for (int p = 0; p < NPART; ++p) {
        size_t pb = (size_t)(p * NN + n) * 32 + r * 2;
        unsigned u0 = __builtin_nontemporal_load(pvh + pb);
        unsigned u1 = __builtin_nontemporal_load(pvh + pb + 1);
        float2 dq = unpack2h(pwh[(size_t)(p * NN + n) * 4 + (r >> 2)]);
        float dp = hsel ? dq.y : dq.x;    // this lane's head mass
        float2 f0 = unpack2h(u0), f1 = unpack2h(u1);
        a0 += dp * f0.x; a1 += dp * f0.y;
        a2 += dp * f1.x; a3 += dp * f1.y;
        ds += dp;
    }
    float inv = 1.f / ds;                 // ds>0: self-loop guarantees mass
    float v0 = a0 * inv + b1[r * 4 + 0];
    float v1 = a1 * inv + b1[r * 4 + 1];
    float v2 = a2 * inv + b1[r * 4 + 2];
    float v3 = a3 * inv + b1[r * 4 + 3];
    v0 = v0 > 0.f ? v0 : __expf(v0) - 1.f;   // ELU fused
    v1 = v1 > 0.f ? v1 : __expf(v1) - 1.f;
    v2 = v2 > 0.f ? v2 : __expf(v2) - 1.f;
    v3 = v3 > 0.f ? v3 : __expf(v3) - 1.f;
    uint2 o;
    o.x = (unsigned)f2bf(v0) | ((unsigned)f2bf(v1) << 16);
    o.y = (unsigned)f2bf(v2) | ((unsigned)f2bf(v3) << 16);
    *(uint2*)(h1e2 + n * 32 + r * 2) = o;
}

// ---------- layer 1 aggregation, single-pass fallback (ws too small) ----------
__global__ __launch_bounds__(256) void k_agg1(
    const int* __restrict__ row, const int* __restrict__ adj,
    const float* __restrict__ al1s, const float* __restrict__ al1d,
    const unsigned* __restrict__ h1b2, const float* __restrict__ b1,
    unsigned* __restrict__ h1e2)
{
    const int wv = threadIdx.x >> 6, lane = threadIdx.x & 63;
    const int n = blockIdx.x * 4 + wv;
    const int q = lane >> 4;
    const int r = lane & 15;
    const int h = r >> 1;
    const float ald = al1d[n * 8 + h];
    const int r0 = row[n], r1 = row[n + 1];

    float dsum = 0.f, ax = 0.f, ay = 0.f, bx = 0.f, by = 0.f;
    for (int i = r0; i < r1; i += 4) {
        int i0 = i + q;
        bool act = i0 < r1;
        int s0 = adj[act ? i0 : r0];
        float w0 = act ? __expf(lrelu(al1s[s0 * 8 + h] + ald)) : 0.f;
        uint2 u0 = *(const uint2*)(h1b2 + s0 * 32 + r * 2);
        dsum += w0;
        ax += w0 * bflo(u0.x);
        ay += w0 * bfhi(u0.x);
        bx += w0 * bflo(u0.y);
        by += w0 * bfhi(u0.y);
    }
    dsum += __shfl_xor(dsum, 16, 64); dsum += __shfl_xor(dsum, 32, 64);
    ax   += __shfl_xor(ax,   16, 64); ax   += __shfl_xor(ax,   32, 64);
    ay   += __shfl_xor(ay,   16, 64); ay   += __shfl_xor(ay,   32, 64);
    bx   += __shfl_xor(bx,   16, 64); bx   += __shfl_xor(bx,   32, 64);
    by   += __shfl_xor(by,   16, 64); by   += __shfl_xor(by,   32, 64);

    float inv = 1.f / dsum;
    float v0 = ax * inv + b1[r * 4 + 0];
    float v1 = ay * inv + b1[r * 4 + 1];
    float v2 = bx * inv + b1[r * 4 + 2];
    float v3 = by * inv + b1[r * 4 + 3];
    v0 = v0 > 0.f ? v0 : __expf(v0) - 1.f;
    v1 = v1 > 0.f ? v1 : __expf(v1) - 1.f;
    v2 = v2 > 0.f ? v2 : __expf(v2) - 1.f;
    v3 = v3 > 0.f ? v3 : __expf(v3) - 1.f;
    if (q == 0) {
        uint2 o;
        o.x = (unsigned)f2bf(v0) | ((unsigned)f2bf(v1) << 16);
        o.y = (unsigned)f2bf(v2) | ((unsigned)f2bf(v3) << 16);
        *(uint2*)(h1e2 + n * 32 + r * 2) = o;
    }
}

// ---------- layer 2 GEMM: h2b = bf16(h1e @ W2), al2s/al2d logits ----------
__global__ __launch_bounds__(256) void k_gemm2(
    const unsigned short* __restrict__ h1e, const float* __restrict__ W2,
    const float* __restrict__ a2s, const float* __restrict__ a2d,
    unsigned short* __restrict__ h2b, float* __restrict__ al2s, float* __restrict__ al2d)
{
    __shared__ float sW[64 * 16];
    const int t = threadIdx.x;
    for (int i = t; i < 64 * 16; i += 256) sW[i] = W2[i];
    __syncthreads();
    const int n = blockIdx.x * 16 + (t >> 4);
    const int k = t & 15;
    if (n >= NN) return;
    const unsigned short* hr = h1e + (size_t)n * 64;
    float acc = 0.f;
    #pragma unroll
    for (int c = 0; c < 64; ++c) acc += bf2f(hr[c]) * sW[c * 16 + k];
    h2b[(size_t)n * 16 + k] = f2bf(acc);
    float vs = acc * a2s[k], vd = acc * a2d[k];
    #pragma unroll
    for (int off = 1; off < 16; off <<= 1) {
        vs += __shfl_xor(vs, off, 64);
        vd += __shfl_xor(vd, off, 64);
    }
    if (k == 0) { al2s[n] = vs; al2d[n] = vd; }
}

// ---------- layer 2 aggregation: 16 edges x 4 lanes, uint2 value loads ----------
__global__ __launch_bounds__(256) void k_agg2(
    const int* __restrict__ row, const int* __restrict__ adj,
    const float* __restrict__ al2s, const float* __restrict__ al2d,
    const unsigned* __restrict__ h2b2, const float* __restrict__ b2,
    float* __restrict__ out)
{
    const int wv = threadIdx.x >> 6, lane = threadIdx.x & 63;
    const int n = blockIdx.x * 4 + wv;
    const float ald = al2d[n];
    const int r0 = row[n], r1 = row[n + 1];

    const int j = lane >> 2;    // edge slot 0..15
    const int r = lane & 3;     // channel quad -> channels 4r..4r+3
    float dsum = 0.f, ax = 0.f, ay = 0.f, bx = 0.f, by = 0.f;
    for (int i = r0; i < r1; i += 16) {
        int i0 = i + j;
        bool act = i0 < r1;
        int s = adj[act ? i0 : r0];
        float w = act ? __expf(lrelu(al2s[s] + ald)) : 0.f;
        uint2 u = *(const uint2*)(h2b2 + s * 8 + r * 2);
        dsum += w;
        ax += w * bflo(u.x);
        ay += w * bfhi(u.x);
        bx += w * bflo(u.y);
        by += w * bfhi(u.y);
    }
    #pragma unroll
    for (int off = 4; off < 64; off <<= 1) {
        dsum += __shfl_xor(dsum, off, 64);
        ax   += __shfl_xor(ax,   off, 64);
        ay   += __shfl_xor(ay,   off, 64);
        bx   += __shfl_xor(bx,   off, 64);
        by   += __shfl_xor(by,   off, 64);
    }
    float inv = 1.f / dsum;
    float v0 = ax * inv + b2[r * 4 + 0];
    float v1 = ay * inv + b2[r * 4 + 1];
    float v2 = bx * inv + b2[r * 4 + 2];
    float v3 = by * inv + b2[r * 4 + 3];

    // log_softmax over 16 channels = 4 lanes x 4
    float mx = fmaxf(fmaxf(v0, v1), fmaxf(v2, v3));
    mx = fmaxf(mx, __shfl_xor(mx, 1, 64));
    mx = fmaxf(mx, __shfl_xor(mx, 2, 64));
    float se = __expf(v0 - mx) + __expf(v1 - mx) + __expf(v2 - mx) + __expf(v3 - mx);
    se += __shfl_xor(se, 1, 64);
    se += __shfl_xor(se, 2, 64);
    float ls = mx + __logf(se);
    if (j == 0)
        *(float4*)(out + (size_t)n * 16 + r * 4) = make_float4(v0 - ls, v1 - ls, v2 - ls, v3 - ls);
}

extern "C" void kernel_launch(void* const* d_in, const int* in_sizes, int n_in,
                              void* d_out, int out_size, void* d_ws, size_t ws_size,
                              hipStream_t stream)
{
    const float* x    = (const float*)d_in[0];
    const int*   eidx = (const int*)d_in[1];
    const float* W1   = (const float*)d_in[2];
    const float* a1s  = (const float*)d_in[3];
    const float* a1d  = (const float*)d_in[4];
    const float* b1   = (const float*)d_in[5];
    const float* W2   = (const float*)d_in[6];
    const float* a2s  = (const float*)d_in[7];
    const float* a2d  = (const float*)d_in[8];
    const float* b2   = (const float*)d_in[9];
    float* out = (float*)d_out;
    float* ws  = (float*)d_ws;

    const int* esrc = eidx;
    const int* edst = eidx + EE;

    int* gcnt = (int*)(ws + OFF_GCNT);
    int* base = (int*)(ws + OFF_BASE);
    int* row  = (int*)(ws + OFF_ROW);
    unsigned* bkt = (unsigned*)(ws + OFF_BKT);
    int* adj  = (int*)(ws + OFF_ADJ);
    unsigned short* h1b = (unsigned short*)(ws + OFF_H1B);
    unsigned short* h1e = (unsigned short*)(ws + OFF_H1E);
    float* al1s  = ws + OFF_AL1S;
    float* al1d  = ws + OFF_AL1D;
    unsigned short* h2b = (unsigned short*)(ws + OFF_H2B);
    float* al2s  = ws + OFF_AL2S;
    float* al2d  = ws + OFF_AL2D;
    int* row2 = (int*)(ws + OFF_ROW2);
    unsigned* pvh = (unsigned*)(ws + OFF_PVH);
    unsigned* pwh = (unsigned*)(ws + OFF_PWH);   // aliases bkt (dead after binC)

    const bool wide = ws_size >= (size_t)OFF_END * 4;

    hipMemsetAsync(gcnt, 0, 392 * sizeof(int), stream);

    k_binA <<<NABLK, 256, 0, stream>>>(esrc, edst, gcnt, bkt);
    k_scanB<<<1,     512, 0, stream>>>(gcnt, base, row);
    k_binC <<<NBKT,  256, 0, stream>>>(gcnt, base, bkt, row, adj, row2, wide ? 1 : 0);

    k_gemm1<<<(NN + 63) / 64, 256, 0, stream>>>(x, W1, a1s, a1d, h1b, al1s, al1d);
    if (wide) {
        k_agg1p<<<(NN / 16) * NPART, 256, 0, stream>>>(row2, adj, al1s, al1d,
                                                       (const unsigned*)h1b, pvh, pwh);
        k_comb1<<<NN / 16, 256, 0, stream>>>(pvh, pwh, b1, (unsigned*)h1e);
    } else {
        k_agg1<<<NN / 4, 256, 0, stream>>>(row, adj, al1s, al1d, (const unsigned*)h1b, b1, (unsigned*)h1e);
    }
    k_gemm2<<<NN / 16, 256, 0, stream>>>(h1e, W2, a2s, a2d, h2b, al2s, al2d);
    k_agg2 <<<NN / 4, 256, 0, stream>>>(row, adj, al2s, al2d, (const unsigned*)h2b, b2, out);
}